// Round 3
// baseline (589.334 us; speedup 1.0000x reference)
//
#include <hip/hip_runtime.h>

// VectorQuantizer: inputs [65536,128] f32, codebook [1024,128] f32.
// Outputs flat f32: loss(1) | quantized_st(65536*128) | perplexity(1) | encodings(65536*1024)
#define NROWS 65536
#define DIM   128
#define KC    1024
#define QST_OFF  1
#define PPL_OFF  8388609
#define ENC_OFF  8388610

typedef float f32x2 __attribute__((ext_vector_type(2)));  // native vec for nontemporal store

// --- rounding-exact helpers: replicate numpy's elementwise fp32 ops, no FMA contraction ---
__device__ __forceinline__ float fadd_rn_(float a, float b) {
#pragma clang fp contract(off)
  return a + b;
}
__device__ __forceinline__ float fsub_rn_(float a, float b) {
#pragma clang fp contract(off)
  return a - b;
}
__device__ __forceinline__ float fmul_rn_(float a, float b) {
#pragma clang fp contract(off)
  return a * b;
}

// K1: row sum-of-squares with numpy pairwise_sum order (n=128: 8 accumulators,
// combine ((r0+r1)+(r2+r3))+((r4+r5)+(r6+r7))).
__global__ __launch_bounds__(256) void k_rowsq(const float* __restrict__ inp,
                                               const float* __restrict__ cb,
                                               float* __restrict__ xx,
                                               float* __restrict__ cc) {
  int tid = blockIdx.x * 256 + threadIdx.x;
  const float* src;
  float* dst;
  if (tid < NROWS) {
    src = inp + (size_t)tid * DIM;
    dst = xx + tid;
  } else if (tid < NROWS + KC) {
    src = cb + (size_t)(tid - NROWS) * DIM;
    dst = cc + (tid - NROWS);
  } else {
    return;
  }
  float r[8];
  {
    float4 v0 = *(const float4*)(src);
    float4 v1 = *(const float4*)(src + 4);
    r[0] = fmul_rn_(v0.x, v0.x); r[1] = fmul_rn_(v0.y, v0.y);
    r[2] = fmul_rn_(v0.z, v0.z); r[3] = fmul_rn_(v0.w, v0.w);
    r[4] = fmul_rn_(v1.x, v1.x); r[5] = fmul_rn_(v1.y, v1.y);
    r[6] = fmul_rn_(v1.z, v1.z); r[7] = fmul_rn_(v1.w, v1.w);
  }
  for (int t = 1; t < 16; ++t) {
    float4 v0 = *(const float4*)(src + t * 8);
    float4 v1 = *(const float4*)(src + t * 8 + 4);
    r[0] = fadd_rn_(r[0], fmul_rn_(v0.x, v0.x));
    r[1] = fadd_rn_(r[1], fmul_rn_(v0.y, v0.y));
    r[2] = fadd_rn_(r[2], fmul_rn_(v0.z, v0.z));
    r[3] = fadd_rn_(r[3], fmul_rn_(v0.w, v0.w));
    r[4] = fadd_rn_(r[4], fmul_rn_(v1.x, v1.x));
    r[5] = fadd_rn_(r[5], fmul_rn_(v1.y, v1.y));
    r[6] = fadd_rn_(r[6], fmul_rn_(v1.z, v1.z));
    r[7] = fadd_rn_(r[7], fmul_rn_(v1.w, v1.w));
  }
  float res = fadd_rn_(fadd_rn_(fadd_rn_(r[0], r[1]), fadd_rn_(r[2], r[3])),
                       fadd_rn_(fadd_rn_(r[4], r[5]), fadd_rn_(r[6], r[7])));
  *dst = res;
}

// K1b: transpose codebook [1024,128] -> cbT [128,1024] so B-fragments are
// contiguous (8 codes at fixed d = 32B) for direct global/L2 reads in k_main.
__global__ __launch_bounds__(256) void k_tr(const float* __restrict__ cb,
                                            float* __restrict__ cbT) {
  __shared__ float tile[64 * 129];  // +1 pad: conflict-free transpose
  int t = threadIdx.x;
  int c0 = blockIdx.x * 64;
#pragma unroll
  for (int it = 0; it < 32; ++it) {
    int f = it * 256 + t;
    int c = f >> 7, d = f & 127;
    tile[c * 129 + d] = cb[(size_t)(c0 + c) * DIM + d];
  }
  __syncthreads();
#pragma unroll
  for (int it = 0; it < 32; ++it) {
    int f = it * 256 + t;
    int d = f >> 6, c = f & 63;
    cbT[(size_t)d * KC + c0 + c] = tile[c * 129 + d];
  }
}

__device__ __forceinline__ void fma_rank1(float (&acc)[4][8], float4 a,
                                          float4 bl, float4 bh) {
  float av[4] = {a.x, a.y, a.z, a.w};
  float bv[8] = {bl.x, bl.y, bl.z, bl.w, bh.x, bh.y, bh.z, bh.w};
#pragma unroll
  for (int i = 0; i < 4; ++i)
#pragma unroll
    for (int j = 0; j < 8; ++j)
      acc[i][j] = __builtin_fmaf(av[i], bv[j], acc[i][j]);
}

// K2: 64 rows/block, 256 threads (16 ty x 16 tx), thread tile 4 rows x 8 codes.
// A staged once in LDS (32 KB, transposed); B read straight from cbT (L2-hot,
// coalesced 32B/lane, 4-way ty broadcast), software-pipelined one d-pair ahead.
// ZERO barriers in the K loop. Epilogue: qst + one-hot encodings + histogram + loss.
__global__ __launch_bounds__(256, 4) void k_main(const float* __restrict__ inp,
                                                 const float* __restrict__ cb,
                                                 const float* __restrict__ cbT,
                                                 const float* __restrict__ xx,
                                                 const float* __restrict__ cc,
                                                 float* __restrict__ out_qst,
                                                 float* __restrict__ out_enc,
                                                 int* __restrict__ cnt,
                                                 float* __restrict__ lsum) {
  __shared__ float As[DIM * 64];  // [d][row], 32 KB
  int t = threadIdx.x;
  int tx = t & 15, ty = t >> 4;
  int ty4 = ty * 4, tx8 = tx * 8;
  int row0 = blockIdx.x * 64;

  float xr[4];
#pragma unroll
  for (int i = 0; i < 4; ++i) xr[i] = xx[row0 + ty4 + i];

  // stage A transposed: thread t -> row t&63, d-segment (t>>6)*32
  {
    int r = t & 63, seg = t >> 6;
    const float* src = inp + (size_t)(row0 + r) * DIM + seg * 32;
#pragma unroll
    for (int i = 0; i < 8; ++i) {
      float4 v = *(const float4*)(src + i * 4);
      int d = seg * 32 + i * 4;
      As[d * 64 + r] = v.x;
      As[(d + 1) * 64 + r] = v.y;
      As[(d + 2) * 64 + r] = v.z;
      As[(d + 3) * 64 + r] = v.w;
    }
  }

  float bestv[4];
  int bestk[4];
#pragma unroll
  for (int i = 0; i < 4; ++i) { bestv[i] = 3.4e38f; bestk[i] = 0; }

  __syncthreads();  // the only pre-epilogue barrier

  for (int kt = 0; kt < 8; ++kt) {
    const float* bp = cbT + kt * 128 + tx8;  // + d*1024 walks d
    float acc[4][8];
#pragma unroll
    for (int i = 0; i < 4; ++i)
#pragma unroll
      for (int j = 0; j < 8; ++j) acc[i][j] = 0.f;

    float4 c0l = *(const float4*)(bp);
    float4 c0h = *(const float4*)(bp + 4);
    float4 c1l = *(const float4*)(bp + KC);
    float4 c1h = *(const float4*)(bp + KC + 4);
    const float* pp = bp + 2 * KC;

    for (int d = 0; d < 126; d += 2) {
      float4 p0l = *(const float4*)(pp);
      float4 p0h = *(const float4*)(pp + 4);
      float4 p1l = *(const float4*)(pp + KC);
      float4 p1h = *(const float4*)(pp + KC + 4);
      pp += 2 * KC;
      float4 a0 = *(const float4*)&As[d * 64 + ty4];
      float4 a1 = *(const float4*)&As[(d + 1) * 64 + ty4];
      fma_rank1(acc, a0, c0l, c0h);
      fma_rank1(acc, a1, c1l, c1h);
      c0l = p0l; c0h = p0h; c1l = p1l; c1h = p1h;
    }
    {  // d = 126, 127 (already resident)
      float4 a0 = *(const float4*)&As[126 * 64 + ty4];
      float4 a1 = *(const float4*)&As[127 * 64 + ty4];
      fma_rank1(acc, a0, c0l, c0h);
      fma_rank1(acc, a1, c1l, c1h);
    }

    // distance = fl(fl(xx+cc) - fl(2*m)) -- numpy-exact; first-index argmin
    float4 ccl = *(const float4*)&cc[kt * 128 + tx8];
    float4 cch = *(const float4*)&cc[kt * 128 + tx8 + 4];
    float cj[8] = {ccl.x, ccl.y, ccl.z, ccl.w, cch.x, cch.y, cch.z, cch.w};
#pragma unroll
    for (int i = 0; i < 4; ++i) {
#pragma unroll
      for (int j = 0; j < 8; ++j) {
        float dist = fsub_rn_(fadd_rn_(xr[i], cj[j]), fmul_rn_(2.0f, acc[i][j]));
        int idx = kt * 128 + tx8 + j;
        if (dist < bestv[i]) { bestv[i] = dist; bestk[i] = idx; }
      }
    }
  }

  // butterfly argmin across the 16 tx lanes (same wave); tie -> lower index
#pragma unroll
  for (int i = 0; i < 4; ++i) {
    float v = bestv[i];
    int k = bestk[i];
    for (int off = 1; off < 16; off <<= 1) {
      float ov = __shfl_xor(v, off);
      int ok = __shfl_xor(k, off);
      if (ov < v || (ov == v && ok < k)) { v = ov; k = ok; }
    }
    bestk[i] = k;
  }

  __syncthreads();  // all As reads done; safe to overlay
  int* bk = (int*)As;          // bk[64] overlay
  float* red = As + 64;        // reduction scratch overlay (disjoint from bk)
  if (tx == 0) {
#pragma unroll
    for (int i = 0; i < 4; ++i) {
      bk[ty4 + i] = bestk[i];
      atomicAdd(&cnt[bestk[i]], 1);
    }
  }
  __syncthreads();

  // quantized_st rows + loss partial (coalesced; x re-read from global, L2-hot)
  float ls = 0.f;
#pragma unroll 4
  for (int it = 0; it < 32; ++it) {
    int f = it * 256 + t;  // 64 rows x 128 d
    int row = f >> 7, d = f & 127;
    size_t gro = (size_t)(row0 + row) * DIM + d;
    float x = inp[gro];
    float q = cb[(size_t)bk[row] * DIM + d];
    float qe = fsub_rn_(q, x);
    __builtin_nontemporal_store(fadd_rn_(x, qe), &out_qst[gro]);
    ls = __builtin_fmaf(qe, qe, ls);
  }

  // encodings rows: full zero+one-hot, nontemporal 8B stores
  for (int it = 0; it < 128; ++it) {
    int f2 = it * 256 + t;  // 64 rows x 512 float2
    int row = f2 >> 9, c2 = f2 & 511;
    int kk = bk[row];
    f32x2 v;
    v.x = (kk == 2 * c2) ? 1.0f : 0.0f;
    v.y = (kk == 2 * c2 + 1) ? 1.0f : 0.0f;
    __builtin_nontemporal_store(v, (f32x2*)&out_enc[(size_t)(row0 + row) * KC + 2 * c2]);
  }

  // block loss reduce -> one atomic
  for (int off = 32; off; off >>= 1) ls += __shfl_down(ls, off);
  if ((t & 63) == 0) red[t >> 6] = ls;
  __syncthreads();
  if (t == 0) {
    float s = red[0] + red[1] + red[2] + red[3];
    atomicAdd(lsum, s);
  }
}

// K3: loss + perplexity scalars
__global__ __launch_bounds__(1024) void k_scalars(const int* __restrict__ cnt,
                                                  const float* __restrict__ lsum,
                                                  float* __restrict__ out) {
  int t = threadIdx.x;
  float p = (float)cnt[t] * (1.0f / 65536.0f);
  float term = fmul_rn_(p, logf(fadd_rn_(p, 1e-10f)));
  for (int off = 32; off; off >>= 1) term += __shfl_down(term, off);
  __shared__ float red[16];
  if ((t & 63) == 0) red[t >> 6] = term;
  __syncthreads();
  if (t == 0) {
    float s = 0.f;
#pragma unroll
    for (int w = 0; w < 16; ++w) s += red[w];
    out[PPL_OFF] = expf(-s);
    float e = *lsum * (1.0f / 8388608.0f);
    out[0] = fadd_rn_(e, fmul_rn_(0.25f, e));  // q_latent + 0.25*e_latent (equal values)
  }
}

extern "C" void kernel_launch(void* const* d_in, const int* in_sizes, int n_in,
                              void* d_out, int out_size, void* d_ws, size_t ws_size,
                              hipStream_t stream) {
  const float* inp = (const float*)d_in[0];
  const float* cb = (const float*)d_in[1];
  float* out = (float*)d_out;
  float* cbT = (float*)d_ws;             // 128*1024 f32 = 512 KB (16B aligned)
  float* xx = cbT + DIM * KC;            // 65536 f32
  float* cc = xx + NROWS;                // 1024 f32
  int* cnt = (int*)(cc + KC);            // 1024 i32
  float* lsum = (float*)(cnt + KC);      // 1 f32

  (void)hipMemsetAsync(cnt, 0, (KC + 1) * sizeof(int), stream);
  k_rowsq<<<(NROWS + KC) / 256, 256, 0, stream>>>(inp, cb, xx, cc);
  k_tr<<<KC / 64, 256, 0, stream>>>(cb, cbT);
  k_main<<<NROWS / 64, 256, 0, stream>>>(inp, cb, cbT, xx, cc,
                                         out + QST_OFF, out + ENC_OFF, cnt, lsum);
  k_scalars<<<1, 1024, 0, stream>>>(cnt, lsum, out);
}